// Round 8
// baseline (238.746 us; speedup 1.0000x reference)
//
#include <hip/hip_runtime.h>

// PCEN: x [32, 256, 4096] fp32. EMA over time per row, then
// out = sqrt(x / (m+eps)^0.98 + 2) - sqrt(2).
//
// ROUND 8: hand-scheduled memory pipeline in inline asm.
// Evidence r2-r7: six structurally different C++ schedules all land at
// 83-94us / ~2.4 TB/s; VGPR_Count (32/60/96) proves the compiler
// serialized every attempted double-buffer (sink + re-materialize is
// legal on readonly __restrict), and the r6/r7 "memory"-clobber fence
// likely forced a full vmcnt(0) drain after each burst (asm that may
// read memory must see all loads complete). The common residue: per-wave
// burst->silent->burst convoy, CU memory pipe ~40% duty.
//
// This version pins the schedule where the compiler can't touch it:
//  - persistent waves: 512 blocks x 4 waves, 4 rows/wave, half-row
//    (2048-elem, 8 x float4/lane) tiles, A/B register double-buffer;
//  - loads = asm volatile global_load_dwordx4 (cannot sink/re-mat);
//  - waits = hand-counted s_waitcnt vmcnt(8) + sched_barrier(0):
//    vmcnt retires in issue order; at each wait the 8 newest ops are the
//    prefetch loads, so vmcnt(8) retires exactly the consumed buffer's
//    loads (+prior stores) and NEVER the prefetch. No vmcnt(0) anywhere
//    in the loop; stores are fire-and-forget.
//  Steady state per wave: compute tile k while tile k+1's 8 loads and
//  tile k-1's 8 stores are in flight -> continuous per-CU memory issue.
//
// Scan math per half-tile (verified passing r0-r2,r5-r7): per-lane
// 4-elem local EMA (coeff A4=0.975^4), 6-step Hillis-Steele wave scan
// (coeffs A4^(2^d)), serial sub-chunk carry chain (coeff A256) fused
// with the exp2/log/sqrt epilogue; carry propagates half0->half1,
// resets to 0 at each row start (m_{-1}=0 reproduces m0=s*x0).

typedef float f32x4 __attribute__((ext_vector_type(4)));

constexpr int T_LEN      = 4096;
constexpr int HALF_ELEMS = 2048;
constexpr int SUBS       = 8;     // float4 sub-chunks per half-tile
constexpr int NROWS_PW   = 4;     // rows per wave
constexpr int WAVES_PER_BLK = 4;
constexpr int NTHR       = 256;

constexpr float EPSF = 1e-6f;
constexpr float SF   = 0.025f;
constexpr float A1F  = 0.975f;

constexpr double dA1   = 0.975;
constexpr double dA2   = dA1 * dA1;
constexpr double dA4   = dA2 * dA2;     // per-lane segment coeff
constexpr double dA8   = dA4 * dA4;
constexpr double dA16  = dA8 * dA8;
constexpr double dA32  = dA16 * dA16;
constexpr double dA64  = dA32 * dA32;
constexpr double dA128 = dA64 * dA64;
constexpr double dA256 = dA128 * dA128; // per-sub-chunk coeff (64 x 4)

// volatile asm load: cannot be sunk below later code, re-materialized,
// or register-minimized away. Destination regs are pinned until use.
#define GLOAD(dst, base, imm)                                        \
    asm volatile("global_load_dwordx4 %0, %1, off offset:" #imm     \
                 : "=v"(dst) : "v"(base))

// counted wait: retire everything except the 8 newest VMEM ops
// (= the prefetch loads). sched_barrier stops hipcc hoisting consumers
// above the wait (rule: asm waitcnt doesn't order register-only uses).
#define VMWAIT8()                                  \
    do {                                           \
        asm volatile("s_waitcnt vmcnt(8)");        \
        __builtin_amdgcn_sched_barrier(0);         \
    } while (0)

#define SBAR() __builtin_amdgcn_sched_barrier(0)

__global__ __launch_bounds__(NTHR) void pcen_pipe_kernel(
    const float* __restrict__ x, float* __restrict__ out, int rows)
{
    const int lane = threadIdx.x & 63;
    const int wave = threadIdx.x >> 6;
    const int NW   = gridDim.x * WAVES_PER_BLK;     // total waves
    const int wid  = blockIdx.x * WAVES_PER_BLK + wave;

    const float cA4   = (float)dA4;
    const float cA8   = (float)dA8;
    const float cA16  = (float)dA16;
    const float cA32  = (float)dA32;
    const float cA64  = (float)dA64;
    const float cA128 = (float)dA128;
    const float cA256 = (float)dA256;

    // lane-constant carry decay: A4^lane
    float flane = 1.0f;
    if (lane & 1)  flane *= cA4;
    if (lane & 2)  flane *= cA8;
    if (lane & 4)  flane *= cA16;
    if (lane & 8)  flane *= cA32;
    if (lane & 16) flane *= cA64;
    if (lane & 32) flane *= cA128;

    const float SQRT_D = 1.41421356237309515f;  // sqrt(2.0)

    // ---- issue one half-tile's 8 loads (asm, stays in flight) ----
    auto issue = [&](f32x4* buf, int r, int h) {
        const float* b0 = x + (long long)r * T_LEN + h * HALF_ELEMS + (lane << 2);
        const float* b1 = b0 + 1024;
        GLOAD(buf[0], b0, 0);
        GLOAD(buf[1], b0, 1024);
        GLOAD(buf[2], b0, 2048);
        GLOAD(buf[3], b0, 3072);
        GLOAD(buf[4], b1, 0);
        GLOAD(buf[5], b1, 1024);
        GLOAD(buf[6], b1, 2048);
        GLOAD(buf[7], b1, 3072);
        SBAR();   // pin: nothing (esp. stores) crosses into/out of the burst
    };

    // ---- scan + fused epilogue + stores for one half-tile ----
    auto process = [&](const f32x4* d, int r, int h, float carry) -> float {
        // per-lane local 4-elem scans (zero init)
        float Sv[SUBS];
#pragma unroll
        for (int s = 0; s < SUBS; ++s) {
            float m = SF * d[s].x;
            m = fmaf(A1F, m, SF * d[s].y);
            m = fmaf(A1F, m, SF * d[s].z);
            m = fmaf(A1F, m, SF * d[s].w);
            Sv[s] = m;
        }
        // 8 independent wave scans, coeff A4^offset
#pragma unroll
        for (int s = 0; s < SUBS; ++s) {
            float tt;
            tt = __shfl_up(Sv[s], 1,  64); if (lane >= 1)  Sv[s] = fmaf(cA4,   tt, Sv[s]);
            tt = __shfl_up(Sv[s], 2,  64); if (lane >= 2)  Sv[s] = fmaf(cA8,   tt, Sv[s]);
            tt = __shfl_up(Sv[s], 4,  64); if (lane >= 4)  Sv[s] = fmaf(cA16,  tt, Sv[s]);
            tt = __shfl_up(Sv[s], 8,  64); if (lane >= 8)  Sv[s] = fmaf(cA32,  tt, Sv[s]);
            tt = __shfl_up(Sv[s], 16, 64); if (lane >= 16) Sv[s] = fmaf(cA64,  tt, Sv[s]);
            tt = __shfl_up(Sv[s], 32, 64); if (lane >= 32) Sv[s] = fmaf(cA128, tt, Sv[s]);
        }
        // serial carry chain fused with epilogue + stores (fire-and-forget)
        float* po = out + (long long)r * T_LEN + h * HALF_ELEMS + (lane << 2);
#pragma unroll
        for (int s = 0; s < SUBS; ++s) {
            float excl = __shfl_up(Sv[s], 1, 64);
            if (lane == 0) excl = 0.0f;
            float last = __shfl(Sv[s], 63, 64);

            float m = fmaf(flane, carry, excl);
            carry   = fmaf(cA256, carry, last);

            f32x4 v = d[s];
            f32x4 o;
            m = fmaf(A1F, m, SF * v.x);
            o.x = __builtin_amdgcn_sqrtf(
                      fmaf(v.x, __builtin_amdgcn_exp2f(
                          -0.98f * __builtin_amdgcn_logf(m + EPSF)), 2.0f)) - SQRT_D;
            m = fmaf(A1F, m, SF * v.y);
            o.y = __builtin_amdgcn_sqrtf(
                      fmaf(v.y, __builtin_amdgcn_exp2f(
                          -0.98f * __builtin_amdgcn_logf(m + EPSF)), 2.0f)) - SQRT_D;
            m = fmaf(A1F, m, SF * v.z);
            o.z = __builtin_amdgcn_sqrtf(
                      fmaf(v.z, __builtin_amdgcn_exp2f(
                          -0.98f * __builtin_amdgcn_logf(m + EPSF)), 2.0f)) - SQRT_D;
            m = fmaf(A1F, m, SF * v.w);
            o.w = __builtin_amdgcn_sqrtf(
                      fmaf(v.w, __builtin_amdgcn_exp2f(
                          -0.98f * __builtin_amdgcn_logf(m + EPSF)), 2.0f)) - SQRT_D;

            *(f32x4*)(po + s * 256) = o;
        }
        SBAR();   // pin: stores stay BEFORE the next load burst (vmcnt order)
        return carry;
    };

    f32x4 A[SUBS], B[SUBS];
    const int r0 = wid;

    if (r0 + 3 * NW < rows) {
        // main path: 4 rows, 8 half-tiles, steady-state A/B pipeline.
        // vmcnt queue at each VMWAIT8 (issue order): [8 oldest: buffer to
        // consume (+retiring stores)] [8 newest: prefetch] -> wait(8)
        // retires exactly the consumed buffer, prefetch stays in flight.
        const int r[4] = { r0, r0 + NW, r0 + 2 * NW, r0 + 3 * NW };
        issue(A, r[0], 0);
#pragma unroll
        for (int k = 0; k < 4; ++k) {
            issue(B, r[k], 1);                    // prefetch half1
            VMWAIT8();                            // A ready; B in flight
            float carry = process(A, r[k], 0, 0.0f);
            if (k < 3) issue(A, r[k + 1], 0);     // prefetch next row half0
            VMWAIT8();                            // B ready; A in flight
            (void)process(B, r[k], 1, carry);
        }
    } else {
        // generic fallback (never taken for rows=8192): plain loads
        for (int rr = r0; rr < rows; rr += NW) {
            float carry = 0.0f;
            f32x4 tmp[SUBS];
            for (int h = 0; h < 2; ++h) {
                const float* pb = x + (long long)rr * T_LEN + h * HALF_ELEMS + (lane << 2);
#pragma unroll
                for (int s = 0; s < SUBS; ++s)
                    tmp[s] = *(const f32x4*)(pb + s * 256);
                carry = process(tmp, rr, h, h ? carry : 0.0f);
            }
        }
    }
}

extern "C" void kernel_launch(void* const* d_in, const int* in_sizes, int n_in,
                              void* d_out, int out_size, void* d_ws, size_t ws_size,
                              hipStream_t stream) {
    const float* x = (const float*)d_in[0];
    float* out = (float*)d_out;
    const int rows = in_sizes[0] / T_LEN;  // 32*256 = 8192
    const int rows_per_blk = NROWS_PW * WAVES_PER_BLK;          // 16
    const int blocks = (rows + rows_per_blk - 1) / rows_per_blk; // 512
    pcen_pipe_kernel<<<dim3(blocks), dim3(NTHR), 0, stream>>>(x, out, rows);
}

// Round 10
// 225.988 us; speedup vs baseline: 1.0565x; 1.0565x over previous
//
#include <hip/hip_runtime.h>

// PCEN: x [32, 256, 4096] fp32. EMA over time per row, then
// out = sqrt(x / (m+eps)^0.98 + 2) - sqrt(2).
//
// ROUND 10: return to the round-0 baseline structure (block-per-row,
// 1024 thr, LDS cross-wave carry) -- the session's 9 alternative
// schedules (wave-per-row, whole-row-in-regs, fences, asm pipelines;
// occupancy 17-58%, VGPR 32-96) ALL landed in the same 78-94us band,
// and the baseline's high-block-turnover operating point (8192 blocks,
// natural chip-wide load/store stagger) is the band's best (~78us).
// Two strictly-local fixes on top of the verified r0 source:
//  1. __fsqrt_rn -> __builtin_amdgcn_sqrtf (raw v_sqrt_f32, no
//     refinement sequence; validated absmax-safe in rounds 5-8).
//  2. The divergent serial 15-iter cross-wave carry loop -> 4-step
//     shuffle mini-scan over the 16 wave totals (each wave redundantly;
//     removes the longest-wave serial tail behind the barrier).
//
// One block per (b,f) row. 1024 threads x 4 elements (one float4) each,
// perfectly coalesced. Scan math: per-thread 4-elem local EMA (coeff
// A4 = 0.975^4), 6-step Hillis-Steele wave scan (coeffs A4^(2^d)),
// cross-wave fixup via LDS wave totals (coeff A256 per wave).

constexpr int T_LEN  = 4096;
constexpr int NTHR   = 1024;
constexpr int PER    = 4;

constexpr float EPSF = 1e-6f;
constexpr float SF   = 0.025f;
constexpr float A1F  = 0.975f;

// exact powers of 0.975 via constexpr repeated squaring
constexpr double dA1    = 0.975;
constexpr double dA2    = dA1 * dA1;
constexpr double dA4    = dA2 * dA2;      // per-thread segment coeff (4 steps)
constexpr double dA8    = dA4 * dA4;
constexpr double dA16   = dA8 * dA8;
constexpr double dA32   = dA16 * dA16;
constexpr double dA64   = dA32 * dA32;
constexpr double dA128  = dA64 * dA64;
constexpr double dA256  = dA128 * dA128;  // per-wave coeff (64 segments x 4)
constexpr double dA512  = dA256 * dA256;
constexpr double dA1024 = dA512 * dA512;
constexpr double dA2048 = dA1024 * dA1024;

__global__ __launch_bounds__(NTHR) void pcen_scan_kernel(
    const float* __restrict__ x, float* __restrict__ out)
{
    const int row  = blockIdx.x;
    const long long base = (long long)row * T_LEN;
    const int tid  = threadIdx.x;
    const int lane = tid & 63;
    const int wave = tid >> 6;

    const float4* __restrict__ px   = (const float4*)(x + base);
    float4* __restrict__       pout = (float4*)(out + base);

    // ---- coalesced load: lane i -> float4 #i ----
    float4 v = px[tid];
    float xv[PER] = { v.x, v.y, v.z, v.w };

    // ---- local scan (zero init) -> segment total ----
    float m = 0.0f;
#pragma unroll
    for (int k = 0; k < PER; ++k) m = fmaf(A1F, m, SF * xv[k]);
    float Sv = m;  // inclusive local total

    // ---- wave-level inclusive scan, coeff A4^offset ----
    const float c1  = (float)dA4;
    const float c2  = (float)dA8;
    const float c4  = (float)dA16;
    const float c8  = (float)dA32;
    const float c16 = (float)dA64;
    const float c32 = (float)dA128;
    const float c64 = (float)dA256;
    float t;
    t = __shfl_up(Sv, 1,  64); if (lane >= 1)  Sv = fmaf(c1,  t, Sv);
    t = __shfl_up(Sv, 2,  64); if (lane >= 2)  Sv = fmaf(c2,  t, Sv);
    t = __shfl_up(Sv, 4,  64); if (lane >= 4)  Sv = fmaf(c4,  t, Sv);
    t = __shfl_up(Sv, 8,  64); if (lane >= 8)  Sv = fmaf(c8,  t, Sv);
    t = __shfl_up(Sv, 16, 64); if (lane >= 16) Sv = fmaf(c16, t, Sv);
    t = __shfl_up(Sv, 32, 64); if (lane >= 32) Sv = fmaf(c32, t, Sv);

    // ---- cross-wave carry (16 waves): parallel 16-scan of wave totals ----
    __shared__ float Wt[NTHR / 64];
    if (lane == 63) Wt[wave] = Sv;
    __syncthreads();

    // each wave redundantly scans the 16 totals in its lanes (groups of 16)
    const float w1 = (float)dA256;
    const float w2 = (float)dA512;
    const float w4 = (float)dA1024;
    const float w8 = (float)dA2048;
    float wv = Wt[lane & 15];
    t = __shfl_up(wv, 1, 16); if ((lane & 15) >= 1) wv = fmaf(w1, t, wv);
    t = __shfl_up(wv, 2, 16); if ((lane & 15) >= 2) wv = fmaf(w2, t, wv);
    t = __shfl_up(wv, 4, 16); if ((lane & 15) >= 4) wv = fmaf(w4, t, wv);
    t = __shfl_up(wv, 8, 16); if ((lane & 15) >= 8) wv = fmaf(w8, t, wv);
    // exclusive prefix for this wave = inclusive at index wave-1 (0 for wave 0)
    const int src = (wave == 0) ? 0 : (wave - 1);
    float cwv = __shfl(wv, src, 64);
    float cw  = (wave == 0) ? 0.0f : cwv;   // m at end of previous wave's region

    // global inclusive value: S_glob = S_local + A4^(lane+1) * cw
    {
        int e = lane + 1;      // 1..64
        float f = 1.0f;
        if (e & 1)  f *= c1;
        if (e & 2)  f *= c2;
        if (e & 4)  f *= c4;
        if (e & 8)  f *= c8;
        if (e & 16) f *= c16;
        if (e & 32) f *= c32;
        if (e & 64) f *= c64;
        Sv = fmaf(f, cw, Sv);
    }
    float carry = __shfl_up(Sv, 1, 64);
    if (lane == 0) carry = cw;   // first thread of wave: carry is wave carry

    // ---- second pass: exact EMA from carry + fused epilogue ----
    const float SQRT_D = 1.41421356237309515f;  // sqrt(2.0)
    float r[PER];
    m = carry;
#pragma unroll
    for (int k = 0; k < PER; ++k) {
        m = fmaf(A1F, m, SF * xv[k]);
        // (m+eps)^-0.98 = exp2(-0.98 * log2(m+eps))
        float p = __builtin_amdgcn_exp2f(-0.98f * __builtin_amdgcn_logf(m + EPSF));
        r[k] = __builtin_amdgcn_sqrtf(fmaf(xv[k], p, 2.0f)) - SQRT_D;
    }

    // ---- coalesced store ----
    pout[tid] = make_float4(r[0], r[1], r[2], r[3]);
}

extern "C" void kernel_launch(void* const* d_in, const int* in_sizes, int n_in,
                              void* d_out, int out_size, void* d_ws, size_t ws_size,
                              hipStream_t stream) {
    const float* x = (const float*)d_in[0];
    float* out = (float*)d_out;
    const int rows = in_sizes[0] / T_LEN;  // 32*256 = 8192
    pcen_scan_kernel<<<dim3(rows), dim3(NTHR), 0, stream>>>(x, out);
}